// Round 1
// baseline (9481.145 us; speedup 1.0000x reference)
//
#include <hip/hip_runtime.h>
#include <math.h>

// ---------------------------------------------------------------------------
// RAFT-small forward on MI355X — round 1: correct baseline.
//
// Key design decision: corr pyramid is NEVER materialized. avg_pool over the
// (u,v) dims of the corr volume commutes with the channel dot product, so
// pyramid level i == corr(f1_fullres, avg_pool^i(f2)). corr_lookup computes
// an 8x8 lattice of dots per level per query pixel and bilinearly combines
// (all 49 window offsets share the same fractional weights).
// Workspace: ~55 MB fp32.
// ---------------------------------------------------------------------------

static inline int nblk(int n, int b){ return (n + b - 1) / b; }

__global__ void k_ew_tanh(const float* __restrict__ in, float* __restrict__ out, int n){
  int i = blockIdx.x*256 + threadIdx.x;
  if (i < n) out[i] = tanhf(in[i]);
}
__global__ void k_ew_relu(const float* __restrict__ in, float* __restrict__ out, int n){
  int i = blockIdx.x*256 + threadIdx.x;
  if (i < n) out[i] = fmaxf(in[i], 0.0f);
}
__global__ void k_copy(const float* __restrict__ in, float* __restrict__ out, int n){
  int i = blockIdx.x*256 + threadIdx.x;
  if (i < n) out[i] = in[i];
}
__global__ void k_init_coords(float* __restrict__ c, int H, int W){
  int p = blockIdx.x*256 + threadIdx.x;
  int HW = H*W;
  if (p < HW){ c[p] = (float)(p % W); c[HW + p] = (float)(p / W); }
}
// [128,HW] (NCHW) -> [HW,128] (HWC)
__global__ void k_transpose_hwc(const float* __restrict__ in, float* __restrict__ out, int HW){
  int i = blockIdx.x*256 + threadIdx.x;
  if (i < HW*128){ int p = i >> 7, c = i & 127; out[i] = in[c*HW + p]; }
}
// 2x2 avg pool on HWC layout
__global__ void k_pool_hwc(const float* __restrict__ in, float* __restrict__ out, int H2, int W2){
  int i = blockIdx.x*256 + threadIdx.x;
  int n = H2*W2*128;
  if (i >= n) return;
  int c = i & 127, p = i >> 7;
  int ox = p % W2, oy = p / W2;
  int W = 2*W2;
  const float* b = in + ((size_t)(2*oy)*W + 2*ox)*128 + c;
  out[i] = 0.25f*(b[0] + b[128] + b[(size_t)W*128] + b[(size_t)W*128 + 128]);
}

// One 64-thread wave per query pixel. For each of 4 levels: lane (u,v) in 8x8
// computes dot(f1[q], f2_level[fx-3+u, fy-3+v]) (0 if OOB); then 49 lanes
// bilinearly combine with the level's shared (wx,wy) and write channel
// level*49 + j*7 + k  (j = x-offset index, k = y-offset index, per reference
// delta = stack([dy,dx]) added to (x,y)).
__global__ void k_corr_lookup(const float* __restrict__ f1,      // [128,HW]
                              const float* __restrict__ l0, const float* __restrict__ l1,
                              const float* __restrict__ l2, const float* __restrict__ l3,
                              const float* __restrict__ coords,  // [2,HW]
                              float* __restrict__ out,           // [196,HW]
                              int H, int W)
{
  int q = blockIdx.x;
  int HW = H*W;
  int t = threadIdx.x;                 // 0..63
  __shared__ __align__(16) float sf1[128];
  __shared__ float sD[64];
  sf1[t]      = f1[(size_t)t*HW + q];
  sf1[t + 64] = f1[(size_t)(t+64)*HW + q];
  __syncthreads();
  float x = coords[q], y = coords[HW + q];
  const float* const lv[4] = {l0, l1, l2, l3};
  int u = t & 7, v = t >> 3;
  #pragma unroll
  for (int i = 0; i < 4; i++){
    int Wi = W >> i, Hi = H >> i;
    float sc = 1.0f / (float)(1 << i);
    float xs = x*sc, ys = y*sc;
    float fx = floorf(xs), fy = floorf(ys);
    float wx = xs - fx, wy = ys - fy;
    float xf = fx + (float)(u - 3);
    float yf = fy + (float)(v - 3);
    float d = 0.0f;
    if (xf >= 0.0f && xf <= (float)(Wi-1) && yf >= 0.0f && yf <= (float)(Hi-1)){
      const float4* a = (const float4*)sf1;
      const float4* b = (const float4*)(lv[i] + ((size_t)((int)yf)*Wi + (int)xf)*128);
      float acc = 0.0f;
      #pragma unroll
      for (int k = 0; k < 32; k++){
        float4 av = a[k], bv = b[k];
        acc += av.x*bv.x + av.y*bv.y + av.z*bv.z + av.w*bv.w;
      }
      d = acc;
    }
    sD[t] = d;       // sD[v*8+u]
    __syncthreads();
    if (t < 49){
      int j = t / 7, k = t % 7;        // j: x-offset, k: y-offset
      float val = (1.f-wx)*(1.f-wy)*sD[ k   *8 + j  ]
                +      wx *(1.f-wy)*sD[ k   *8 + j+1]
                + (1.f-wx)*     wy *sD[(k+1)*8 + j  ]
                +      wx *     wy *sD[(k+1)*8 + j+1];
      out[(size_t)(i*49 + t)*HW + q] = val * 0.08838834764831845f;  // 1/sqrt(128)
    }
    __syncthreads();
  }
}

__global__ void k_flow_from_coords(const float* __restrict__ coords, float* __restrict__ flow,
                                   int H, int W){
  int p = blockIdx.x*256 + threadIdx.x;
  int HW = H*W;
  if (p < HW){
    flow[p]      = coords[p]      - (float)(p % W);
    flow[HW + p] = coords[HW + p] - (float)(p / W);
  }
}
__global__ void k_rnet(const float* __restrict__ r, const float* __restrict__ net,
                       float* __restrict__ hx, int n){
  int i = blockIdx.x*256 + threadIdx.x;
  if (i < n) hx[i] = r[i] * net[i];
}
__global__ void k_gru(const float* __restrict__ z, const float* __restrict__ q,
                      float* __restrict__ net, int n){
  int i = blockIdx.x*256 + threadIdx.x;
  if (i < n){ float zz = z[i]; net[i] = (1.0f - zz)*net[i] + zz*q[i]; }
}
__global__ void k_add(float* __restrict__ a, const float* __restrict__ b, int n){
  int i = blockIdx.x*256 + threadIdx.x;
  if (i < n) a[i] += b[i];
}

// bilinear upsample, align_corners=True, times n; optionally subtract the
// coords0 grid at the source taps (for flow = coords1 - coords0).
__global__ void k_upflow(const float* __restrict__ cin, float* __restrict__ outp,
                         int Hin, int Win, int Hout, int Wout, float n, int subtract)
{
  int idx = blockIdx.x*256 + threadIdx.x;
  int HWo = Hout*Wout;
  if (idx >= 2*HWo) return;
  int c = idx / HWo;
  int rem = idx - c*HWo;
  int py = rem / Wout, px = rem % Wout;
  float posy = (float)py * (float)(Hin-1) / (float)(Hout-1);
  float posx = (float)px * (float)(Win-1) / (float)(Wout-1);
  int iy = (int)floorf(posy); iy = max(0, min(iy, Hin-2));
  int ix = (int)floorf(posx); ix = max(0, min(ix, Win-2));
  float wy = posy - (float)iy, wx = posx - (float)ix;
  const float* base = cin + (size_t)c*Hin*Win;
  float s00 = 0.f, s10 = 0.f, s01 = 0.f, s11 = 0.f;
  if (subtract){
    if (c == 0){ s00 = (float)ix; s01 = (float)ix; s10 = (float)(ix+1); s11 = (float)(ix+1); }
    else       { s00 = (float)iy; s10 = (float)iy; s01 = (float)(iy+1); s11 = (float)(iy+1); }
  }
  float v00 = base[(size_t)iy*Win + ix]       - s00;
  float v10 = base[(size_t)iy*Win + ix + 1]   - s10;
  float v01 = base[(size_t)(iy+1)*Win + ix]   - s01;
  float v11 = base[(size_t)(iy+1)*Win + ix+1] - s11;
  float val = (1.f-wy)*((1.f-wx)*v00 + wx*v10) + wy*((1.f-wx)*v01 + wx*v11);
  outp[idx] = n * val;
}

// Direct conv, NCHW, OIHW weights, pad=K/2, stride 1.
// 4 output channels per thread; weight indices are wave-uniform (scalar loads).
// ACT: 0 none, 1 relu, 2 sigmoid, 3 tanh.
template<int ACT, int K>
__global__ void k_conv(const float* __restrict__ in, const float* __restrict__ w,
                       const float* __restrict__ bias, float* __restrict__ out,
                       int Cin, int Cout, int H, int W)
{
  const int pad = K/2;
  const int KK = K*K;
  int HW = H*W;
  int pix = blockIdx.x*256 + threadIdx.x;
  if (pix >= HW) return;
  int x = pix % W, y = pix / W;
  int co0 = blockIdx.y*4;
  int c1 = min(co0+1, Cout-1), c2 = min(co0+2, Cout-1), c3 = min(co0+3, Cout-1);
  const float* w0 = w + (size_t)co0*Cin*KK;
  const float* w1 = w + (size_t)c1 *Cin*KK;
  const float* w2 = w + (size_t)c2 *Cin*KK;
  const float* w3 = w + (size_t)c3 *Cin*KK;
  float a0 = 0.f, a1 = 0.f, a2 = 0.f, a3 = 0.f;
  for (int ci = 0; ci < Cin; ci++){
    const float* ip = in + (size_t)ci*HW;
    int wb = ci*KK;
    #pragma unroll
    for (int ky = 0; ky < K; ky++){
      int yy = y + ky - pad;
      if ((unsigned)yy >= (unsigned)H) continue;
      const float* rp = ip + (size_t)yy*W;
      #pragma unroll
      for (int kx = 0; kx < K; kx++){
        int xx = x + kx - pad;
        if ((unsigned)xx >= (unsigned)W) continue;
        float vv = rp[xx];
        int wi = wb + ky*K + kx;
        a0 += vv * w0[wi];
        a1 += vv * w1[wi];
        a2 += vv * w2[wi];
        a3 += vv * w3[wi];
      }
    }
  }
  float r0 = a0 + bias[co0];
  float r1 = a1 + bias[c1];
  float r2 = a2 + bias[c2];
  float r3 = a3 + bias[c3];
  auto act = [](float v)->float{
    if (ACT == 1) return fmaxf(v, 0.0f);
    if (ACT == 2) return 1.0f/(1.0f + expf(-v));
    if (ACT == 3) return tanhf(v);
    return v;
  };
  out[(size_t)co0*HW + pix] = act(r0);
  if (co0+1 < Cout) out[(size_t)(co0+1)*HW + pix] = act(r1);
  if (co0+2 < Cout) out[(size_t)(co0+2)*HW + pix] = act(r2);
  if (co0+3 < Cout) out[(size_t)(co0+3)*HW + pix] = act(r3);
}

extern "C" void kernel_launch(void* const* d_in, const int* in_sizes, int n_in,
                              void* d_out, int out_size, void* d_ws, size_t ws_size,
                              hipStream_t stream)
{
  (void)in_sizes; (void)n_in; (void)out_size; (void)ws_size;
  // input order per setup_inputs
  const float* f1s[3]    = {(const float*)d_in[0], (const float*)d_in[2], (const float*)d_in[4]};
  const float* f2s[3]    = {(const float*)d_in[1], (const float*)d_in[3], (const float*)d_in[5]};
  const float* net_in[3] = {(const float*)d_in[6], (const float*)d_in[8], (const float*)d_in[10]};
  const float* inp_in[3] = {(const float*)d_in[7], (const float*)d_in[9], (const float*)d_in[11]};
  const float* Wc1 = (const float*)d_in[12]; const float* bc1 = (const float*)d_in[13];
  const float* Wf1 = (const float*)d_in[14]; const float* bf1 = (const float*)d_in[15];
  const float* Wf2 = (const float*)d_in[16]; const float* bf2 = (const float*)d_in[17];
  const float* Wm  = (const float*)d_in[18]; const float* bm  = (const float*)d_in[19];
  const float* Wz  = (const float*)d_in[20]; const float* bz  = (const float*)d_in[21];
  const float* Wr  = (const float*)d_in[22]; const float* br  = (const float*)d_in[23];
  const float* Wq  = (const float*)d_in[24]; const float* bq  = (const float*)d_in[25];
  const float* Wh1 = (const float*)d_in[26]; const float* bh1 = (const float*)d_in[27];
  const float* Wh2 = (const float*)d_in[28]; const float* bh2 = (const float*)d_in[29];

  const int Hs[3] = {96, 48, 24};    // si: 0 -> s=2, 1 -> s=4, 2 -> s=8

  float* ws = (float*)d_ws;
  size_t off = 0;
  auto alloc = [&](size_t nfl)->float*{
    float* p = ws + off;
    off += (nfl + 3) & ~((size_t)3);   // 16B-aligned chunks
    return p;
  };

  float* f2l[3][4]; float* netb[3]; float* inpb[3]; float* coords[3];
  for (int si = 0; si < 3; si++){
    int H = Hs[si], HW = H*H;
    for (int l = 0; l < 4; l++) f2l[si][l] = alloc((size_t)(HW >> (2*l))*128);
    netb[si]   = alloc((size_t)96*HW);
    inpb[si]   = alloc((size_t)64*HW);
    coords[si] = alloc((size_t)2*HW);
  }
  const int HWm = 96*96;
  float* corrfeat = alloc((size_t)196*HWm);
  float* flo1     = alloc((size_t)64*HWm);
  float* cmin     = alloc((size_t)128*HWm);   // [cor(96), flo2(32)]
  float* hx       = alloc((size_t)242*HWm);   // [net 96 | inp 64 | mot 80 | flow 2]
  float* zb       = alloc((size_t)96*HWm);
  float* rb       = alloc((size_t)96*HWm);
  float* qb       = alloc((size_t)96*HWm);
  float* t128     = alloc((size_t)128*HWm);
  float* dfb      = alloc((size_t)2*HWm);

  #define NB(n) dim3((unsigned)nblk((n), 256))

  // ---- per-scale init: activations, coords grid, pooled-f2 pyramid (HWC) ----
  for (int si = 0; si < 3; si++){
    int H = Hs[si], HW = H*H;
    k_ew_tanh<<<NB(96*HW), 256, 0, stream>>>(net_in[si], netb[si], 96*HW);
    k_ew_relu<<<NB(64*HW), 256, 0, stream>>>(inp_in[si], inpb[si], 64*HW);
    k_init_coords<<<NB(HW), 256, 0, stream>>>(coords[si], H, H);
    k_transpose_hwc<<<NB(HW*128), 256, 0, stream>>>(f2s[si], f2l[si][0], HW);
    for (int l = 1; l < 4; l++){
      int Hl = H >> l;
      k_pool_hwc<<<NB(Hl*Hl*128), 256, 0, stream>>>(f2l[si][l-1], f2l[si][l], Hl, Hl);
    }
  }

  // ---- 6 update iterations: SCALES = (8,8,4,4,2,2) ----
  const int seq[6] = {2, 2, 1, 1, 0, 0};
  for (int it = 0; it < 6; it++){
    int si = seq[it];
    int H = Hs[si], W = H, HW = H*W;
    float s = (si == 0) ? 2.0f : ((si == 1) ? 4.0f : 8.0f);
    dim3 blk(256);

    k_corr_lookup<<<dim3((unsigned)HW), 64, 0, stream>>>(
        f1s[si], f2l[si][0], f2l[si][1], f2l[si][2], f2l[si][3],
        coords[si], corrfeat, H, W);
    k_flow_from_coords<<<NB(HW), 256, 0, stream>>>(coords[si], hx + (size_t)240*HW, H, W);
    k_copy<<<NB(96*HW), 256, 0, stream>>>(netb[si], hx, 96*HW);
    k_copy<<<NB(64*HW), 256, 0, stream>>>(inpb[si], hx + (size_t)96*HW, 64*HW);

    // SmallMotionEncoder
    k_conv<1,1><<<dim3((unsigned)nblk(HW,256), 96/4), blk, 0, stream>>>(corrfeat, Wc1, bc1, cmin, 196, 96, H, W);
    k_conv<1,7><<<dim3((unsigned)nblk(HW,256), 64/4), blk, 0, stream>>>(hx + (size_t)240*HW, Wf1, bf1, flo1, 2, 64, H, W);
    k_conv<1,3><<<dim3((unsigned)nblk(HW,256), 32/4), blk, 0, stream>>>(flo1, Wf2, bf2, cmin + (size_t)96*HW, 64, 32, H, W);
    k_conv<1,3><<<dim3((unsigned)nblk(HW,256), 80/4), blk, 0, stream>>>(cmin, Wm, bm, hx + (size_t)160*HW, 128, 80, H, W);

    // ConvGRU
    k_conv<2,3><<<dim3((unsigned)nblk(HW,256), 96/4), blk, 0, stream>>>(hx, Wz, bz, zb, 242, 96, H, W);
    k_conv<2,3><<<dim3((unsigned)nblk(HW,256), 96/4), blk, 0, stream>>>(hx, Wr, br, rb, 242, 96, H, W);
    k_rnet<<<NB(96*HW), 256, 0, stream>>>(rb, netb[si], hx, 96*HW);
    k_conv<3,3><<<dim3((unsigned)nblk(HW,256), 96/4), blk, 0, stream>>>(hx, Wq, bq, qb, 242, 96, H, W);
    k_gru<<<NB(96*HW), 256, 0, stream>>>(zb, qb, netb[si], 96*HW);

    // FlowHead
    k_conv<1,3><<<dim3((unsigned)nblk(HW,256), 128/4), blk, 0, stream>>>(netb[si], Wh1, bh1, t128, 96, 128, H, W);
    k_conv<0,3><<<dim3((unsigned)nblk(HW,256), 1), blk, 0, stream>>>(t128, Wh2, bh2, dfb, 128, 2, H, W);

    k_add<<<NB(2*HW), 256, 0, stream>>>(coords[si], dfb, 2*HW);

    // prediction: upflow_n(coords1 - coords0, s) -> out slot `it`
    k_upflow<<<NB(2*192*192), 256, 0, stream>>>(coords[si], (float*)d_out + (size_t)it*2*192*192,
                                                H, W, 192, 192, s, 1);
    // coarse-to-fine handoff: coords1[s/2] = upflow_n(coords1[s], 2)
    if (si > 0){
      int Hf = Hs[si-1];
      k_upflow<<<NB(2*Hf*Hf), 256, 0, stream>>>(coords[si], coords[si-1], H, W, Hf, Hf, 2.0f, 0);
    }
  }
  #undef NB
}